// Round 2
// baseline (125.835 us; speedup 1.0000x reference)
//
#include <hip/hip_runtime.h>
#include <math.h>
#include <stdint.h>

#define B_ 16
#define L_ 50
#define LU_ 60
#define KU_ 100
#define DIM_ 60
#define V_ 2000
#define MAXVL_ 10
#define MIN_WL_ 4
#define MAX_WL_ 10
#define NE_ 7            // MAX_WL - MIN_WL + 1
#define IDC_ 3.5f
#define LOG_UNEXT_ (-4.6051701859880913680359829093687f)  // log(0.01)
#define CTXW_ 0.1f
#define NQ_ 13           // l-quads per batch row (13*4 >= 50)

// workspace layout (bytes)
#define WS_PLP  0                  // pos_lp: B*L*KU = 80000 floats
#define WS_BEST_BYTES (80000u * 4u)       // 320000: 16 padded u64 slots
#define BEST_STRIDE 8              // 64 B between per-batch atomic slots
#define WS_VPACK_BYTES (WS_BEST_BYTES + 1024u)  // 321024 (16B aligned): 2000 int4

#define URP_ 61   // padded LDS stride (odd -> conflict-free strided reads)
#define CWP_ 61
#define RKP_ 104  // DP tile row stride in floats: 16B multiple (float4 staging),
                  // scalar gathers at random k hit banks (k + 8*row) % 32 ~ free

// -------------------------------------------------------------------------
// Kernel 1: fused prep+ctx, one block per (b, l-quad) = 208 blocks, plus one
// extra block (blk==208) that counting-sorts vocab by length into vpack
// (int4 per entry: 3 byte-packed vid dwords + (vlen | v<<8)).
// Blocks 0..59 additionally emit alignment row r=blk; block 0 zeroes g_best.
__global__ __launch_bounds__(256) void ctx_kernel(
    const int* __restrict__ uid,        // (B, L)
    const float* __restrict__ unit_repr,// (KU, DIM)
    const float* __restrict__ aligner_w,// (LU, KU)
    const float* __restrict__ conv_w,   // (DIM, DIM, 3)
    const float* __restrict__ conv_b,   // (DIM,)
    const int* __restrict__ vocab_ids,  // (V, MAXVL)
    const int* __restrict__ vocab_lengths, // (V,)
    float* __restrict__ ws_plp,         // (B*L, KU)
    float* __restrict__ out_align,      // (LU, KU)
    unsigned long long* __restrict__ g_best,
    int* __restrict__ vpack)            // (V, int4)
{
  int blk = blockIdx.x;
  int t = threadIdx.x;

  // ---- sort block: counting-sort vocab by vlen, pack ids
  if (blk == B_ * NQ_) {
    __shared__ unsigned scnt[NE_];
    if (t < NE_) scnt[t] = 0u;
    __syncthreads();
    for (int v = t; v < V_; v += 256)
      atomicAdd(&scnt[vocab_lengths[v] - MIN_WL_], 1u);
    __syncthreads();
    if (t == 0) {
      unsigned s = 0;
      for (int e = 0; e < NE_; ++e) { unsigned c = scnt[e]; scnt[e] = s; s += c; }
    }
    __syncthreads();
    for (int v = t; v < V_; v += 256) {
      int vl = vocab_lengths[v];
      unsigned dst = atomicAdd(&scnt[vl - MIN_WL_], 1u);
      unsigned q0 = 0u, q1 = 0u, q2 = 0u;
#pragma unroll
      for (int j = 0; j < 4; ++j) q0 |= ((unsigned)vocab_ids[v * MAXVL_ + j]) << (j * 8);
#pragma unroll
      for (int j = 0; j < 4; ++j) q1 |= ((unsigned)vocab_ids[v * MAXVL_ + 4 + j]) << (j * 8);
#pragma unroll
      for (int j = 0; j < 2; ++j) q2 |= ((unsigned)vocab_ids[v * MAXVL_ + 8 + j]) << (j * 8);
      int4 w;
      w.x = (int)q0; w.y = (int)q1; w.z = (int)q2;
      w.w = (int)((unsigned)vl | ((unsigned)v << 8));
      ((int4*)vpack)[dst] = w;
    }
    return;
  }

  int b = blk / NQ_, q = blk % NQ_;
  int l0 = 4 * q;
  int npos = (l0 + 4 <= L_) ? 4 : (L_ - l0);
  int alr = (blk < LU_) ? blk : -1;

  __shared__ float s_ur[KU_ * URP_];       // unit_repr padded (6100)
  __shared__ float s_cw[3 * DIM_ * CWP_];  // conv_w transposed (10980)
  __shared__ float s_aw[7 * KU_];          // 6 neighborhood aligner rows + align row
  __shared__ float s_kx[7 * DIM_];         // 6 ku rows + align ku row
  __shared__ float swr[4 * DIM_];          // conv outputs
  __shared__ float sclp[4 * KU_];          // char logits per position
  __shared__ float sctx[4 * KU_];          // ctx logits per position
  __shared__ float salg[KU_];              // align logits
  __shared__ float sls[9];                 // 8 pos logsumexps + align

  if (blk == 0 && t < B_) g_best[t * BEST_STRIDE] = 0ull;

  // --- P0: stage weights (float4 global) + aligner rows
  const float4* ur4 = (const float4*)unit_repr;
  for (int k = t; k < (KU_ * DIM_) / 4; k += 256) {
    float4 v = ur4[k];
    int i0 = 4 * k;
    s_ur[((i0 + 0) / DIM_) * URP_ + ((i0 + 0) % DIM_)] = v.x;
    s_ur[((i0 + 1) / DIM_) * URP_ + ((i0 + 1) % DIM_)] = v.y;
    s_ur[((i0 + 2) / DIM_) * URP_ + ((i0 + 2) % DIM_)] = v.z;
    s_ur[((i0 + 3) / DIM_) * URP_ + ((i0 + 3) % DIM_)] = v.w;
  }
  const float4* cw4 = (const float4*)conv_w;
  for (int k = t; k < (DIM_ * DIM_ * 3) / 4; k += 256) {
    float4 v = cw4[k];
    int i0 = 4 * k;
    float vv[4] = {v.x, v.y, v.z, v.w};
#pragma unroll
    for (int e = 0; e < 4; ++e) {
      int idx = i0 + e;
      int o = idx / (3 * DIM_), id = idx % (3 * DIM_);
      s_cw[id * CWP_ + o] = vv[e];
    }
  }
  for (int i = t; i < 7 * KU_; i += 256) {
    int m = i / KU_, k = i - m * KU_;
    float w = 0.f;
    if (m < 6) {
      int ld = l0 - 1 + m;
      if (ld >= 0 && ld < L_) {
        int u = uid[b * L_ + ld];
        w = aligner_w[u * KU_ + k];
      }
    } else if (alr >= 0) {
      w = aligner_w[alr * KU_ + k];
    }
    s_aw[i] = w;
  }
  __syncthreads();

  // --- P1: ku rows (420 outputs, 100 MACs)
  for (int idx = t; idx < 7 * DIM_; idx += 256) {
    int m = idx / DIM_, c = idx - m * DIM_;
    const float4* aw4 = (const float4*)&s_aw[m * KU_];
    float acc = 0.f;
    for (int k4 = 0; k4 < KU_ / 4; ++k4) {
      float4 a = aw4[k4];
      int k = 4 * k4;
      acc += a.x * s_ur[(k + 0) * URP_ + c];
      acc += a.y * s_ur[(k + 1) * URP_ + c];
      acc += a.z * s_ur[(k + 2) * URP_ + c];
      acc += a.w * s_ur[(k + 3) * URP_ + c];
    }
    s_kx[idx] = acc;
  }
  __syncthreads();

  // --- P2: conv (240) + char logits (400)
  for (int idx = t; idx < 240 + 4 * KU_; idx += 256) {
    if (idx < 240) {
      int p = idx / DIM_, o = idx - p * DIM_;
      const float4* x04 = (const float4*)&s_kx[(p + 0) * DIM_];
      const float4* x14 = (const float4*)&s_kx[(p + 1) * DIM_];
      const float4* x24 = (const float4*)&s_kx[(p + 2) * DIM_];
      float acc = conv_b[o];
      for (int i4 = 0; i4 < DIM_ / 4; ++i4) {
        float4 x0 = x04[i4], x1 = x14[i4], x2 = x24[i4];
        int i = 4 * i4;
        acc += x0.x * s_cw[((i + 0) * 3 + 0) * CWP_ + o];
        acc += x1.x * s_cw[((i + 0) * 3 + 1) * CWP_ + o];
        acc += x2.x * s_cw[((i + 0) * 3 + 2) * CWP_ + o];
        acc += x0.y * s_cw[((i + 1) * 3 + 0) * CWP_ + o];
        acc += x1.y * s_cw[((i + 1) * 3 + 1) * CWP_ + o];
        acc += x2.y * s_cw[((i + 1) * 3 + 2) * CWP_ + o];
        acc += x0.z * s_cw[((i + 2) * 3 + 0) * CWP_ + o];
        acc += x1.z * s_cw[((i + 2) * 3 + 1) * CWP_ + o];
        acc += x2.z * s_cw[((i + 2) * 3 + 2) * CWP_ + o];
        acc += x0.w * s_cw[((i + 3) * 3 + 0) * CWP_ + o];
        acc += x1.w * s_cw[((i + 3) * 3 + 1) * CWP_ + o];
        acc += x2.w * s_cw[((i + 3) * 3 + 2) * CWP_ + o];
      }
      swr[p * DIM_ + o] = acc;
    } else {
      int r = idx - 240;
      int p = r / KU_, j = r - p * KU_;
      const float4* kx4 = (const float4*)&s_kx[(p + 1) * DIM_];
      float acc = 0.f;
      for (int d4 = 0; d4 < DIM_ / 4; ++d4) {
        float4 x = kx4[d4];
        int d = 4 * d4;
        acc += x.x * s_ur[j * URP_ + d + 0];
        acc += x.y * s_ur[j * URP_ + d + 1];
        acc += x.z * s_ur[j * URP_ + d + 2];
        acc += x.w * s_ur[j * URP_ + d + 3];
      }
      sclp[r] = acc;
    }
  }
  __syncthreads();

  // --- P3: ctx logits (400) + align logits (100)
  for (int idx = t; idx < 4 * KU_ + KU_; idx += 256) {
    if (idx < 4 * KU_) {
      int p = idx / KU_, j = idx - p * KU_;
      const float4* w4 = (const float4*)&swr[p * DIM_];
      float acc = 0.f;
      for (int d4 = 0; d4 < DIM_ / 4; ++d4) {
        float4 x = w4[d4];
        int d = 4 * d4;
        acc += x.x * s_ur[j * URP_ + d + 0];
        acc += x.y * s_ur[j * URP_ + d + 1];
        acc += x.z * s_ur[j * URP_ + d + 2];
        acc += x.w * s_ur[j * URP_ + d + 3];
      }
      sctx[idx] = acc;
    } else {
      int j = idx - 4 * KU_;
      const float4* kx4 = (const float4*)&s_kx[6 * DIM_];
      float acc = 0.f;
      for (int d4 = 0; d4 < DIM_ / 4; ++d4) {
        float4 x = kx4[d4];
        int d = 4 * d4;
        acc += x.x * s_ur[j * URP_ + d + 0];
        acc += x.y * s_ur[j * URP_ + d + 1];
        acc += x.z * s_ur[j * URP_ + d + 2];
        acc += x.w * s_ur[j * URP_ + d + 3];
      }
      salg[j] = acc;
    }
  }
  __syncthreads();

  // --- P4: 9 logsumexp reductions (8 groups of 32 lanes, 2 rounds)
  {
    int g = t >> 5, lane = t & 31;
#pragma unroll
    for (int round = 0; round < 2; ++round) {
      int r = round * 8 + g;
      if (r < 9) {
        const float* arr = (r == 8) ? salg
                          : ((r & 1) ? &sctx[(r >> 1) * KU_] : &sclp[(r >> 1) * KU_]);
        float v1 = arr[lane];
        float v2 = arr[32 + lane];
        float v3 = arr[64 + lane];
        float v4 = (lane < KU_ - 96) ? arr[96 + lane] : -1e30f;
        float mx = fmaxf(fmaxf(v1, v2), fmaxf(v3, v4));
#pragma unroll
        for (int off = 16; off > 0; off >>= 1)
          mx = fmaxf(mx, __shfl_xor(mx, off));
        float s = expf(v1 - mx) + expf(v2 - mx) + expf(v3 - mx) +
                  ((lane < KU_ - 96) ? expf(v4 - mx) : 0.f);
#pragma unroll
        for (int off = 16; off > 0; off >>= 1)
          s += __shfl_xor(s, off);
        if (lane == 0) sls[r] = mx + logf(s);
      }
    }
  }
  __syncthreads();

  // --- P5: guarded outputs
  for (int idx = t; idx < 4 * KU_; idx += 256) {
    int p = idx / KU_, j = idx - p * KU_;
    if (p < npos) {
      float pos = (sclp[idx] - sls[2 * p]) + CTXW_ * (sctx[idx] - sls[2 * p + 1]);
      ws_plp[(b * L_ + l0 + p) * KU_ + j] = pos;
    }
  }
  if (alr >= 0 && t < KU_)
    out_align[alr * KU_ + t] = expf(salg[t] - sls[8]);
}

// -------------------------------------------------------------------------
// Kernel 2: DP with i OUTER / j INNER and a ROW-MAJOR LDS tile.
// Round-1 evidence: column-major gathers (stride 48B ds_read_b128) were
// ~8-way bank-conflicted (SQ_LDS_BANK_CONFLICT ~2.0M) and LDS-pipe-bound.
// Here each cell reads one scalar srow[(i-1)*RKP + k_j]: random k over 32
// banks ~ conflict-free, row offset folds into the ds_read offset imm
// (both loops unrolled). A-row update uses a one-slot delay so all array
// indices stay compile-time (no scratch). 2 vocab/thread from vlen-sorted
// vpack (wave-uniform vlen -> execz skips trailing j). Grid (B*L, 4) x 256.
__global__ __launch_bounds__(256) void dp_kernel(
    const int* __restrict__ lengths,
    const float* __restrict__ ws_plp,       // (B*L, KU)
    const int* __restrict__ vpack,          // (V, int4) sorted by vlen
    unsigned long long* __restrict__ g_best)
{
  int bl = blockIdx.x;
  int b = bl / L_, l = bl % L_;
  int len_b = lengths[b];
  int imax = len_b - l;
  if (imax > MAX_WL_) imax = MAX_WL_;
  if (imax < MIN_WL_) return;       // uniform across block

  __shared__ float srow[MAX_WL_ * RKP_];   // srow[r*104 + k], r = i-1
  __shared__ unsigned long long swave[4];
  int t = threadIdx.x;
  // Stage all 10 rows unconditionally (1 float4/thread). Rows r >= imax may
  // read past this (b,l)'s valid range (still inside the workspace buffer);
  // their values only feed computations whose captures are masked (i<=imax),
  // and v_max_f32 absorbs NaN, so garbage is harmless.
  if (t < 250) {
    const float4* src = (const float4*)(ws_plp + (size_t)bl * KU_);
    int r = t / 25, m = t - r * 25;
    float4 v = src[r * 25 + m];
    *(float4*)&srow[r * RKP_ + 4 * m] = v;
  }
  __syncthreads();

  int p = blockIdx.y * 256 + t;     // 0..1023; entries 2p, 2p+1
  const int4* vp4 = (const int4*)vpack;
  int4 w0 = (2 * p < V_) ? vp4[2 * p] : make_int4(0, 0, 0, 0);
  int4 w1 = (2 * p + 1 < V_) ? vp4[2 * p + 1] : make_int4(0, 0, 0, 0);
  int vlen0 = (int)((unsigned)w0.w & 0xFFu);      // 0 when invalid -> no capture
  int vlen1 = (int)((unsigned)w1.w & 0xFFu);
  int v0 = (int)(((unsigned)w0.w) >> 8);
  int v1 = (int)(((unsigned)w1.w) >> 8);
  int jmax = (vlen0 > vlen1) ? vlen0 : vlen1;

  // pre-unpack k byte-offsets (k*4), 20 VGPRs
  int koff0[MAXVL_], koff1[MAXVL_];
  {
    unsigned q0[3] = {(unsigned)w0.x, (unsigned)w0.y, (unsigned)w0.z};
    unsigned q1[3] = {(unsigned)w1.x, (unsigned)w1.y, (unsigned)w1.z};
#pragma unroll
    for (int j = 0; j < MAXVL_; ++j) {
      koff0[j] = (int)((q0[j >> 2] >> ((j & 3) * 8)) & 0xFFu) * 4;
      koff1[j] = (int)((q1[j >> 2] >> ((j & 3) * 8)) & 0xFFu) * 4;
    }
  }

  float A0[MAXVL_ + 1], A1[MAXVL_ + 1];   // previous DP row (SSA after unroll)
#pragma unroll
  for (int i = 0; i <= MAXVL_; ++i) {
    A0[i] = -IDC_ * (float)i;
    A1[i] = A0[i];
  }

  float bestSc0 = -1e30f, bestSc1 = -1e30f;
  int bestI0 = 0, bestI1 = 0;
  const char* sbase = (const char*)srow;

#pragma unroll
  for (int i = 1; i <= MAX_WL_; ++i) {
    float b0 = -IDC_ * (float)i;           // B[0]
    float b1 = b0;
    float ci = (float)(len_b - i) * LOG_UNEXT_;   // uniform -> scalar pipe
    bool iok = (i <= imax);                        // uniform
#pragma unroll
    for (int j = 1; j <= MAXVL_; ++j) {
      if (j <= jmax) {                     // wave-near-uniform after sort
        float s0 = *(const float*)(sbase + (i - 1) * (RKP_ * 4) + koff0[j - 1]);
        float s1 = *(const float*)(sbase + (i - 1) * (RKP_ * 4) + koff1[j - 1]);
        float n0 = fmaxf(A0[j - 1] + s0, fmaxf(A0[j] - IDC_, b0 - IDC_));
        float n1 = fmaxf(A1[j - 1] + s1, fmaxf(A1[j] - IDC_, b1 - IDC_));
        A0[j - 1] = b0; A1[j - 1] = b1;    // delayed write-back (static idx)
        b0 = n0; b1 = n1;
        if (i >= MIN_WL_) {                // compile-time prune
          if (iok && j == vlen0) {
            float sc = n0 + ci;
            if (sc > bestSc0) { bestSc0 = sc; bestI0 = i; }   // strict >: first i wins ties
          }
          if (iok && j == vlen1) {
            float sc = n1 + ci;
            if (sc > bestSc1) { bestSc1 = sc; bestI1 = i; }
          }
        }
      } else if (j == jmax + 1) {          // finalize A[jmax] without dyn index
        A0[j - 1] = b0; A1[j - 1] = b1;
      }
    }
    if (jmax == MAXVL_) { A0[MAXVL_] = b0; A1[MAXVL_] = b1; }
  }

  unsigned long long bestKey = 0ull;
  if (bestI0 > 0) {
    unsigned int idx = (unsigned int)(l * (NE_ * V_) + (bestI0 - MIN_WL_) * V_ + v0);
    unsigned int u = __float_as_uint(bestSc0);
    u = (u & 0x80000000u) ? ~u : (u | 0x80000000u);
    unsigned long long key = ((unsigned long long)u << 32) | (unsigned long long)(~idx);
    if (key > bestKey) bestKey = key;
  }
  if (bestI1 > 0) {
    unsigned int idx = (unsigned int)(l * (NE_ * V_) + (bestI1 - MIN_WL_) * V_ + v1);
    unsigned int u = __float_as_uint(bestSc1);
    u = (u & 0x80000000u) ? ~u : (u | 0x80000000u);
    unsigned long long key = ((unsigned long long)u << 32) | (unsigned long long)(~idx);
    if (key > bestKey) bestKey = key;
  }

#pragma unroll
  for (int off = 32; off > 0; off >>= 1) {
    unsigned long long o = __shfl_down(bestKey, off);
    if (o > bestKey) bestKey = o;
  }
  int wid = t >> 6;
  if ((t & 63) == 0) swave[wid] = bestKey;
  __syncthreads();
  if (t == 0) {
    unsigned long long k0 = swave[0];
    for (int w = 1; w < 4; ++w)
      if (swave[w] > k0) k0 = swave[w];
    atomicMax(g_best + (size_t)b * BEST_STRIDE, k0);
  }
}

// -------------------------------------------------------------------------
// Kernel 3: decode. Separate launch = implicit device-wide fence (cheap).
__global__ void decode_kernel(const unsigned long long* __restrict__ g_best,
                              float* __restrict__ out)
{
  int t = threadIdx.x;
  if (t < B_) {
    unsigned long long key = g_best[t * BEST_STRIDE];
    unsigned int u = (unsigned int)(key >> 32);
    unsigned int idx = ~((unsigned int)(key & 0xFFFFFFFFull));
    unsigned int bits = (u & 0x80000000u) ? (u & 0x7FFFFFFFu) : ~u;
    float val = __uint_as_float(bits);
    int start = (int)(idx / (NE_ * V_));
    int rem = (int)(idx % (NE_ * V_));
    int e = rem / V_;
    int vv = rem % V_;
    out[t] = (float)start;
    out[B_ + t] = (float)(start + MIN_WL_ + e - 1);
    out[2 * B_ + t] = val;
    out[3 * B_ + t] = (float)vv;
  }
}

// -------------------------------------------------------------------------
extern "C" void kernel_launch(void* const* d_in, const int* in_sizes, int n_in,
                              void* d_out, int out_size, void* d_ws, size_t ws_size,
                              hipStream_t stream)
{
  const int* uid            = (const int*)d_in[0];
  const int* lengths        = (const int*)d_in[1];
  const float* unit_repr    = (const float*)d_in[2];
  const float* aligner_w    = (const float*)d_in[3];
  const float* conv_w       = (const float*)d_in[4];
  const float* conv_b       = (const float*)d_in[5];
  const int* vocab_ids      = (const int*)d_in[6];
  const int* vocab_lengths  = (const int*)d_in[7];
  float* out = (float*)d_out;
  float* ws_f = (float*)d_ws;
  unsigned long long* g_best =
      (unsigned long long*)((char*)d_ws + WS_BEST_BYTES);
  int* vpack = (int*)((char*)d_ws + WS_VPACK_BYTES);

  ctx_kernel<<<B_ * NQ_ + 1, 256, 0, stream>>>(uid, unit_repr, aligner_w,
                                               conv_w, conv_b, vocab_ids,
                                               vocab_lengths, ws_f + WS_PLP,
                                               out + 4 * B_, g_best, vpack);
  dim3 g3(B_ * L_, 4);
  dp_kernel<<<g3, 256, 0, stream>>>(lengths, ws_f + WS_PLP, vpack, g_best);
  decode_kernel<<<1, 64, 0, stream>>>(g_best, out);
}

// Round 3
// 101.960 us; speedup vs baseline: 1.2342x; 1.2342x over previous
//
#include <hip/hip_runtime.h>
#include <math.h>
#include <stdint.h>

#define B_ 16
#define L_ 50
#define LU_ 60
#define KU_ 100
#define DIM_ 60
#define V_ 2000
#define MAXVL_ 10
#define MIN_WL_ 4
#define MAX_WL_ 10
#define NE_ 7            // MAX_WL - MIN_WL + 1
#define IDC_ 3.5f
#define LOG_UNEXT_ (-4.6051701859880913680359829093687f)  // log(0.01)
#define CTXW_ 0.1f
#define NQ_ 13           // l-quads per batch row (13*4 >= 50)

// workspace layout (bytes)
#define WS_PLP  0                  // pos_lp(+2*IDC): B*L*KU = 80000 floats
#define WS_BEST_BYTES (80000u * 4u)       // 320000: 16 padded u64 slots
#define BEST_STRIDE 8              // 64 B between per-batch atomic slots
#define WS_VPACK_BYTES (WS_BEST_BYTES + 1024u)  // 321024 (16B aligned): 2000 int4

#define URP_ 61   // padded LDS stride (odd -> conflict-free strided reads)
#define CWP_ 61
#define SP2_ 208  // row-pair stride in floats: spair[r2*208 + 2*k + h], h=row&1

// -------------------------------------------------------------------------
// Kernel 1: fused prep+ctx (208 blocks) + vocab counting-sort (block 208).
// NOTE: ws_plp now stores pos_lp + 2*IDC (potential-transformed DP operand;
// ws_plp has no other consumer). out_align unchanged.
__global__ __launch_bounds__(256) void ctx_kernel(
    const int* __restrict__ uid,        // (B, L)
    const float* __restrict__ unit_repr,// (KU, DIM)
    const float* __restrict__ aligner_w,// (LU, KU)
    const float* __restrict__ conv_w,   // (DIM, DIM, 3)
    const float* __restrict__ conv_b,   // (DIM,)
    const int* __restrict__ vocab_ids,  // (V, MAXVL)
    const int* __restrict__ vocab_lengths, // (V,)
    float* __restrict__ ws_plp,         // (B*L, KU)
    float* __restrict__ out_align,      // (LU, KU)
    unsigned long long* __restrict__ g_best,
    int* __restrict__ vpack)            // (V, int4)
{
  int blk = blockIdx.x;
  int t = threadIdx.x;

  // ---- sort block: counting-sort vocab by vlen, pack ids
  if (blk == B_ * NQ_) {
    __shared__ unsigned scnt[NE_];
    if (t < NE_) scnt[t] = 0u;
    __syncthreads();
    for (int v = t; v < V_; v += 256)
      atomicAdd(&scnt[vocab_lengths[v] - MIN_WL_], 1u);
    __syncthreads();
    if (t == 0) {
      unsigned s = 0;
      for (int e = 0; e < NE_; ++e) { unsigned c = scnt[e]; scnt[e] = s; s += c; }
    }
    __syncthreads();
    for (int v = t; v < V_; v += 256) {
      int vl = vocab_lengths[v];
      unsigned dst = atomicAdd(&scnt[vl - MIN_WL_], 1u);
      unsigned q0 = 0u, q1 = 0u, q2 = 0u;
#pragma unroll
      for (int j = 0; j < 4; ++j) q0 |= ((unsigned)vocab_ids[v * MAXVL_ + j]) << (j * 8);
#pragma unroll
      for (int j = 0; j < 4; ++j) q1 |= ((unsigned)vocab_ids[v * MAXVL_ + 4 + j]) << (j * 8);
#pragma unroll
      for (int j = 0; j < 2; ++j) q2 |= ((unsigned)vocab_ids[v * MAXVL_ + 8 + j]) << (j * 8);
      int4 w;
      w.x = (int)q0; w.y = (int)q1; w.z = (int)q2;
      w.w = (int)((unsigned)vl | ((unsigned)v << 8));
      ((int4*)vpack)[dst] = w;
    }
    return;
  }

  int b = blk / NQ_, q = blk % NQ_;
  int l0 = 4 * q;
  int npos = (l0 + 4 <= L_) ? 4 : (L_ - l0);
  int alr = (blk < LU_) ? blk : -1;

  __shared__ float s_ur[KU_ * URP_];       // unit_repr padded (6100)
  __shared__ float s_cw[3 * DIM_ * CWP_];  // conv_w transposed (10980)
  __shared__ float s_aw[7 * KU_];          // 6 neighborhood aligner rows + align row
  __shared__ float s_kx[7 * DIM_];         // 6 ku rows + align ku row
  __shared__ float swr[4 * DIM_];          // conv outputs
  __shared__ float sclp[4 * KU_];          // char logits per position
  __shared__ float sctx[4 * KU_];          // ctx logits per position
  __shared__ float salg[KU_];              // align logits
  __shared__ float sls[9];                 // 8 pos logsumexps + align

  if (blk == 0 && t < B_) g_best[t * BEST_STRIDE] = 0ull;

  // --- P0: stage weights (float4 global) + aligner rows
  const float4* ur4 = (const float4*)unit_repr;
  for (int k = t; k < (KU_ * DIM_) / 4; k += 256) {
    float4 v = ur4[k];
    int i0 = 4 * k;
    s_ur[((i0 + 0) / DIM_) * URP_ + ((i0 + 0) % DIM_)] = v.x;
    s_ur[((i0 + 1) / DIM_) * URP_ + ((i0 + 1) % DIM_)] = v.y;
    s_ur[((i0 + 2) / DIM_) * URP_ + ((i0 + 2) % DIM_)] = v.z;
    s_ur[((i0 + 3) / DIM_) * URP_ + ((i0 + 3) % DIM_)] = v.w;
  }
  const float4* cw4 = (const float4*)conv_w;
  for (int k = t; k < (DIM_ * DIM_ * 3) / 4; k += 256) {
    float4 v = cw4[k];
    int i0 = 4 * k;
    float vv[4] = {v.x, v.y, v.z, v.w};
#pragma unroll
    for (int e = 0; e < 4; ++e) {
      int idx = i0 + e;
      int o = idx / (3 * DIM_), id = idx % (3 * DIM_);
      s_cw[id * CWP_ + o] = vv[e];
    }
  }
  for (int i = t; i < 7 * KU_; i += 256) {
    int m = i / KU_, k = i - m * KU_;
    float w = 0.f;
    if (m < 6) {
      int ld = l0 - 1 + m;
      if (ld >= 0 && ld < L_) {
        int u = uid[b * L_ + ld];
        w = aligner_w[u * KU_ + k];
      }
    } else if (alr >= 0) {
      w = aligner_w[alr * KU_ + k];
    }
    s_aw[i] = w;
  }
  __syncthreads();

  // --- P1: ku rows (420 outputs, 100 MACs)
  for (int idx = t; idx < 7 * DIM_; idx += 256) {
    int m = idx / DIM_, c = idx - m * DIM_;
    const float4* aw4 = (const float4*)&s_aw[m * KU_];
    float acc = 0.f;
    for (int k4 = 0; k4 < KU_ / 4; ++k4) {
      float4 a = aw4[k4];
      int k = 4 * k4;
      acc += a.x * s_ur[(k + 0) * URP_ + c];
      acc += a.y * s_ur[(k + 1) * URP_ + c];
      acc += a.z * s_ur[(k + 2) * URP_ + c];
      acc += a.w * s_ur[(k + 3) * URP_ + c];
    }
    s_kx[idx] = acc;
  }
  __syncthreads();

  // --- P2: conv (240) + char logits (400)
  for (int idx = t; idx < 240 + 4 * KU_; idx += 256) {
    if (idx < 240) {
      int p = idx / DIM_, o = idx - p * DIM_;
      const float4* x04 = (const float4*)&s_kx[(p + 0) * DIM_];
      const float4* x14 = (const float4*)&s_kx[(p + 1) * DIM_];
      const float4* x24 = (const float4*)&s_kx[(p + 2) * DIM_];
      float acc = conv_b[o];
      for (int i4 = 0; i4 < DIM_ / 4; ++i4) {
        float4 x0 = x04[i4], x1 = x14[i4], x2 = x24[i4];
        int i = 4 * i4;
        acc += x0.x * s_cw[((i + 0) * 3 + 0) * CWP_ + o];
        acc += x1.x * s_cw[((i + 0) * 3 + 1) * CWP_ + o];
        acc += x2.x * s_cw[((i + 0) * 3 + 2) * CWP_ + o];
        acc += x0.y * s_cw[((i + 1) * 3 + 0) * CWP_ + o];
        acc += x1.y * s_cw[((i + 1) * 3 + 1) * CWP_ + o];
        acc += x2.y * s_cw[((i + 1) * 3 + 2) * CWP_ + o];
        acc += x0.z * s_cw[((i + 2) * 3 + 0) * CWP_ + o];
        acc += x1.z * s_cw[((i + 2) * 3 + 1) * CWP_ + o];
        acc += x2.z * s_cw[((i + 2) * 3 + 2) * CWP_ + o];
        acc += x0.w * s_cw[((i + 3) * 3 + 0) * CWP_ + o];
        acc += x1.w * s_cw[((i + 3) * 3 + 1) * CWP_ + o];
        acc += x2.w * s_cw[((i + 3) * 3 + 2) * CWP_ + o];
      }
      swr[p * DIM_ + o] = acc;
    } else {
      int r = idx - 240;
      int p = r / KU_, j = r - p * KU_;
      const float4* kx4 = (const float4*)&s_kx[(p + 1) * DIM_];
      float acc = 0.f;
      for (int d4 = 0; d4 < DIM_ / 4; ++d4) {
        float4 x = kx4[d4];
        int d = 4 * d4;
        acc += x.x * s_ur[j * URP_ + d + 0];
        acc += x.y * s_ur[j * URP_ + d + 1];
        acc += x.z * s_ur[j * URP_ + d + 2];
        acc += x.w * s_ur[j * URP_ + d + 3];
      }
      sclp[r] = acc;
    }
  }
  __syncthreads();

  // --- P3: ctx logits (400) + align logits (100)
  for (int idx = t; idx < 4 * KU_ + KU_; idx += 256) {
    if (idx < 4 * KU_) {
      int p = idx / KU_, j = idx - p * KU_;
      const float4* w4 = (const float4*)&swr[p * DIM_];
      float acc = 0.f;
      for (int d4 = 0; d4 < DIM_ / 4; ++d4) {
        float4 x = w4[d4];
        int d = 4 * d4;
        acc += x.x * s_ur[j * URP_ + d + 0];
        acc += x.y * s_ur[j * URP_ + d + 1];
        acc += x.z * s_ur[j * URP_ + d + 2];
        acc += x.w * s_ur[j * URP_ + d + 3];
      }
      sctx[idx] = acc;
    } else {
      int j = idx - 4 * KU_;
      const float4* kx4 = (const float4*)&s_kx[6 * DIM_];
      float acc = 0.f;
      for (int d4 = 0; d4 < DIM_ / 4; ++d4) {
        float4 x = kx4[d4];
        int d = 4 * d4;
        acc += x.x * s_ur[j * URP_ + d + 0];
        acc += x.y * s_ur[j * URP_ + d + 1];
        acc += x.z * s_ur[j * URP_ + d + 2];
        acc += x.w * s_ur[j * URP_ + d + 3];
      }
      salg[j] = acc;
    }
  }
  __syncthreads();

  // --- P4: 9 logsumexp reductions
  {
    int g = t >> 5, lane = t & 31;
#pragma unroll
    for (int round = 0; round < 2; ++round) {
      int r = round * 8 + g;
      if (r < 9) {
        const float* arr = (r == 8) ? salg
                          : ((r & 1) ? &sctx[(r >> 1) * KU_] : &sclp[(r >> 1) * KU_]);
        float v1 = arr[lane];
        float v2 = arr[32 + lane];
        float v3 = arr[64 + lane];
        float v4 = (lane < KU_ - 96) ? arr[96 + lane] : -1e30f;
        float mx = fmaxf(fmaxf(v1, v2), fmaxf(v3, v4));
#pragma unroll
        for (int off = 16; off > 0; off >>= 1)
          mx = fmaxf(mx, __shfl_xor(mx, off));
        float s = expf(v1 - mx) + expf(v2 - mx) + expf(v3 - mx) +
                  ((lane < KU_ - 96) ? expf(v4 - mx) : 0.f);
#pragma unroll
        for (int off = 16; off > 0; off >>= 1)
          s += __shfl_xor(s, off);
        if (lane == 0) sls[r] = mx + logf(s);
      }
    }
  }
  __syncthreads();

  // --- P5: guarded outputs (pos_lp + 2*IDC: DP potential-transform operand)
  for (int idx = t; idx < 4 * KU_; idx += 256) {
    int p = idx / KU_, j = idx - p * KU_;
    if (p < npos) {
      float pos = (sclp[idx] - sls[2 * p]) + CTXW_ * (sctx[idx] - sls[2 * p + 1]);
      ws_plp[(b * L_ + l0 + p) * KU_ + j] = pos + 2.0f * IDC_;
    }
  }
  if (alr >= 0 && t < KU_)
    out_align[alr * KU_ + t] = expf(salg[t] - sls[8]);
}

// -------------------------------------------------------------------------
// DP core, specialized per vocab length VL (vocab is vlen-sorted, so waves
// are near-uniform in VL -> one exec path per wave).
// Potential transform D[i][j] = B[i][j] + IDC*(i+j):
//   D[i][j] = max3(D[i-1][j-1] + s2, D[i-1][j], D[i][j-1]),  s2 = s + 2*IDC
//   D[0][j] = D[i][0] = 0
//   B[i][VL] = D[i][VL] - IDC*(i+VL)
// -> per cell exactly 1 v_add + 1 v_max3 (fmaxf pair fuses), no boundary init.
// spair layout: spair[r2*SP2_ + 2*k + h] holds row (2*r2+h), col k ->
// one ds_read_b64 per (column, row-pair) fetches both rows' operands.
template<int VL>
__device__ __forceinline__ unsigned long long dp_one(
    const float* __restrict__ spair, const int* koff8,
    int imax, int len_b, int l, int v)
{
  float D[VL + 1];
#pragma unroll
  for (int j = 0; j <= VL; ++j) D[j] = 0.f;
  float bestSc = -1e30f;
  int bestI = 0;
  const char* sb = (const char*)spair;

#pragma unroll
  for (int r2 = 0; r2 < 5; ++r2) {
    const int i1 = 2 * r2 + 1, i2 = 2 * r2 + 2;
    if (i1 <= imax) {                 // block-uniform -> scalar branch
      float2 pv[VL];
#pragma unroll
      for (int j = 0; j < VL; ++j)
        pv[j] = *(const float2*)(sb + r2 * (SP2_ * 4) + koff8[j]);
      // row i1 (uses pv[].x)
      float left = 0.f;
#pragma unroll
      for (int j = 1; j <= VL; ++j) {
        float nv = fmaxf(D[j - 1] + pv[j - 1].x, fmaxf(D[j], left));
        D[j - 1] = left;
        left = nv;
      }
      D[VL] = left;
      if (i1 >= MIN_WL_) {            // compile-time
        float sc = left + ((float)(len_b - i1) * LOG_UNEXT_ - IDC_ * (float)(i1 + VL));
        if (sc > bestSc) { bestSc = sc; bestI = i1; }  // strict >: smallest i wins
      }
      // row i2 (uses pv[].y)
      if (i2 <= imax) {               // block-uniform
        left = 0.f;
#pragma unroll
        for (int j = 1; j <= VL; ++j) {
          float nv = fmaxf(D[j - 1] + pv[j - 1].y, fmaxf(D[j], left));
          D[j - 1] = left;
          left = nv;
        }
        D[VL] = left;
        if (i2 >= MIN_WL_) {          // compile-time
          float sc = left + ((float)(len_b - i2) * LOG_UNEXT_ - IDC_ * (float)(i2 + VL));
          if (sc > bestSc) { bestSc = sc; bestI = i2; }
        }
      }
    }
  }
  if (bestI == 0) return 0ull;
  unsigned idx = (unsigned)(l * (NE_ * V_) + (bestI - MIN_WL_) * V_ + v);
  unsigned u = __float_as_uint(bestSc);
  u = (u & 0x80000000u) ? ~u : (u | 0x80000000u);
  return ((unsigned long long)u << 32) | (unsigned long long)(~idx);
}

// -------------------------------------------------------------------------
// Kernel 2: DP, 1 vocab/thread, grid (B*L, 8) x 256.
__global__ __launch_bounds__(256) void dp_kernel(
    const int* __restrict__ lengths,
    const float* __restrict__ ws_plp,       // (B*L, KU), pre-shifted by +2*IDC
    const int* __restrict__ vpack,          // (V, int4) sorted by vlen
    unsigned long long* __restrict__ g_best)
{
  int bl = blockIdx.x;
  int b = bl / L_, l = bl % L_;
  int len_b = lengths[b];
  int imax = len_b - l;
  if (imax > MAX_WL_) imax = MAX_WL_;
  if (imax < MIN_WL_) return;       // uniform across block

  __shared__ float spair[5 * SP2_];        // row-pair interleaved tile (4160 B)
  __shared__ unsigned long long swave[4];
  int t = threadIdx.x;
  // Stage rows 0..9 (rows >= imax may over-read within the workspace; they
  // are never consumed: row-pair guards skip i > imax entirely).
  if (t < 250) {
    const float4* src = (const float4*)(ws_plp + (size_t)bl * KU_);
    int r = t / 25, m = t - r * 25;        // r 0..9, m 0..24 (k = 4m..4m+3)
    float4 v = src[r * 25 + m];
    int r2 = r >> 1, h = r & 1;
    float* dst = &spair[r2 * SP2_ + 8 * m + h];
    dst[0] = v.x; dst[2] = v.y; dst[4] = v.z; dst[6] = v.w;
  }
  __syncthreads();

  int p = blockIdx.y * 256 + t;            // 0..2047; entry p
  const int4* vp4 = (const int4*)vpack;
  int4 w0 = (p < V_) ? vp4[p] : make_int4(0, 0, 0, 0);
  int vlen = (int)((unsigned)w0.w & 0xFFu);      // 0 when invalid
  int v0 = (int)(((unsigned)w0.w) >> 8);

  // k byte-offsets into spair: 2*k floats = 8*k bytes
  int koff8[MAXVL_];
  {
    unsigned q[3] = {(unsigned)w0.x, (unsigned)w0.y, (unsigned)w0.z};
#pragma unroll
    for (int j = 0; j < MAXVL_; ++j)
      koff8[j] = (int)((q[j >> 2] >> ((j & 3) * 8)) & 0xFFu) * 8;
  }

  unsigned long long bestKey = 0ull;
  // vlen-sorted -> wave-uniform dispatch (boundary waves run 2 paths)
  if (vlen == 4)       bestKey = dp_one<4>(spair, koff8, imax, len_b, l, v0);
  else if (vlen == 5)  bestKey = dp_one<5>(spair, koff8, imax, len_b, l, v0);
  else if (vlen == 6)  bestKey = dp_one<6>(spair, koff8, imax, len_b, l, v0);
  else if (vlen == 7)  bestKey = dp_one<7>(spair, koff8, imax, len_b, l, v0);
  else if (vlen == 8)  bestKey = dp_one<8>(spair, koff8, imax, len_b, l, v0);
  else if (vlen == 9)  bestKey = dp_one<9>(spair, koff8, imax, len_b, l, v0);
  else if (vlen == 10) bestKey = dp_one<10>(spair, koff8, imax, len_b, l, v0);

#pragma unroll
  for (int off = 32; off > 0; off >>= 1) {
    unsigned long long o = __shfl_down(bestKey, off);
    if (o > bestKey) bestKey = o;
  }
  int wid = t >> 6;
  if ((t & 63) == 0) swave[wid] = bestKey;
  __syncthreads();
  if (t == 0) {
    unsigned long long k0 = swave[0];
    for (int w = 1; w < 4; ++w)
      if (swave[w] > k0) k0 = swave[w];
    atomicMax(g_best + (size_t)b * BEST_STRIDE, k0);
  }
}

// -------------------------------------------------------------------------
// Kernel 3: decode. Separate launch = implicit device-wide fence (cheap).
__global__ void decode_kernel(const unsigned long long* __restrict__ g_best,
                              float* __restrict__ out)
{
  int t = threadIdx.x;
  if (t < B_) {
    unsigned long long key = g_best[t * BEST_STRIDE];
    unsigned int u = (unsigned int)(key >> 32);
    unsigned int idx = ~((unsigned int)(key & 0xFFFFFFFFull));
    unsigned int bits = (u & 0x80000000u) ? (u & 0x7FFFFFFFu) : ~u;
    float val = __uint_as_float(bits);
    int start = (int)(idx / (NE_ * V_));
    int rem = (int)(idx % (NE_ * V_));
    int e = rem / V_;
    int vv = rem % V_;
    out[t] = (float)start;
    out[B_ + t] = (float)(start + MIN_WL_ + e - 1);
    out[2 * B_ + t] = val;
    out[3 * B_ + t] = (float)vv;
  }
}

// -------------------------------------------------------------------------
extern "C" void kernel_launch(void* const* d_in, const int* in_sizes, int n_in,
                              void* d_out, int out_size, void* d_ws, size_t ws_size,
                              hipStream_t stream)
{
  const int* uid            = (const int*)d_in[0];
  const int* lengths        = (const int*)d_in[1];
  const float* unit_repr    = (const float*)d_in[2];
  const float* aligner_w    = (const float*)d_in[3];
  const float* conv_w       = (const float*)d_in[4];
  const float* conv_b       = (const float*)d_in[5];
  const int* vocab_ids      = (const int*)d_in[6];
  const int* vocab_lengths  = (const int*)d_in[7];
  float* out = (float*)d_out;
  float* ws_f = (float*)d_ws;
  unsigned long long* g_best =
      (unsigned long long*)((char*)d_ws + WS_BEST_BYTES);
  int* vpack = (int*)((char*)d_ws + WS_VPACK_BYTES);

  ctx_kernel<<<B_ * NQ_ + 1, 256, 0, stream>>>(uid, unit_repr, aligner_w,
                                               conv_w, conv_b, vocab_ids,
                                               vocab_lengths, ws_f + WS_PLP,
                                               out + 4 * B_, g_best, vpack);
  dim3 g3(B_ * L_, 8);
  dp_kernel<<<g3, 256, 0, stream>>>(lengths, ws_f + WS_PLP, vpack, g_best);
  decode_kernel<<<1, 64, 0, stream>>>(g_best, out);
}